// Round 5
// baseline (191.173 us; speedup 1.0000x reference)
//
#include <hip/hip_runtime.h>

// Problem constants (fixed by the reference): B=32, N=128, L=16, F=32, NAVG=50
#define BB 32
#define NN 128
#define LL 16
#define FF 32
constexpr float INV_NAVG = 1.0f / 50.0f;

// ---------------------------------------------------------------------------
// Kernel A: per 4 rows (b,i):
//   rs[b,i,l]   = (1/NAVG) * sum_j in[b,i,j,l]          (scaled rowsum)
//   rw3[b,i,f]  = sum_l rs[b,i,l] * w[l,3,f]            (op3 j-broadcast vec)
//   tsp[blk,l]  = sum over the block's 4 rows of rs     (partial totsum)
// 1024 blocks x 256 threads. Coalesced float4 loads, LDS tree reduce.
// ---------------------------------------------------------------------------
__global__ __launch_bounds__(256) void k_rowsum(const float* __restrict__ in,
                                                const float* __restrict__ w,
                                                float* __restrict__ rs,
                                                float* __restrict__ tsp,
                                                float* __restrict__ rw3) {
    __shared__ float4 red4[4][256];      // 16KB
    const int t = threadIdx.x;
    const int blk = blockIdx.x;
    const int rowBase = blk * 4;         // global row = b*128 + i
    const int b = rowBase >> 7, i0 = rowBase & 127;

    const float4* in4 = reinterpret_cast<const float4*>(in);
#pragma unroll
    for (int r = 0; r < 4; ++r) {
        size_t base = (size_t)(rowBase + r) * (NN * LL / 4);   // 512 float4/row
        float4 u = in4[base + t];
        float4 v = in4[base + t + 256];
        float4 a;
        a.x = u.x + v.x; a.y = u.y + v.y; a.z = u.z + v.z; a.w = u.w + v.w;
        red4[r][t] = a;
    }
    __syncthreads();
#pragma unroll
    for (int s = 32; s >= 1; s >>= 1) {          // reduce j-groups: 64 -> 1
        if (t < s * 4) {
#pragma unroll
            for (int r = 0; r < 4; ++r) {
                float4 a = red4[r][t], c = red4[r][t + s * 4];
                a.x += c.x; a.y += c.y; a.z += c.z; a.w += c.w;
                red4[r][t] = a;
            }
        }
        __syncthreads();
    }
    // red4[r][0..3] now hold the RAW row sums (16 floats per row) for all threads.

    if (t < 16) {
        // scaled rowsum write (r = row, c = float4 chunk)
        int r = t >> 2, c = t & 3;
        float4 v = red4[r][c];
        v.x *= INV_NAVG; v.y *= INV_NAVG; v.z *= INV_NAVG; v.w *= INV_NAVG;
        reinterpret_cast<float4*>(rs)[(size_t)(rowBase + r) * 4 + c] = v;

        // partial totsum for l = t: sum over this block's 4 rows (scaled)
        int cc = t >> 2, comp = t & 3;
        float s = 0.f;
#pragma unroll
        for (int r2 = 0; r2 < 4; ++r2)
            s += reinterpret_cast<const float*>(&red4[r2][cc])[comp];
        tsp[(size_t)blk * LL + t] = s * INV_NAVG;   // slot = blk&31, b = blk>>5
    }

    if (t < 128) {   // rw3 for the block's 4 rows (reads red4 broadcast)
        int r = t >> 5, f = t & 31;
        const float* rowRaw = reinterpret_cast<const float*>(&red4[r][0]);
        float v = 0.f;
#pragma unroll
        for (int q = 0; q < LL; ++q)
            v += rowRaw[q] * w[(q * 6 + 3) * FF + f];
        rw3[((size_t)b * NN + i0 + r) * FF + f] = v * INV_NAVG;
    }
}

// ---------------------------------------------------------------------------
// Kernel M: main. 4096 blocks (one (b,i) row each) x 256 threads, 8 blocks/CU.
// Stage input row in LDS; reduce tsp -> totsum in-block; a2s/rwDs per block;
// hot loop touches only LDS + one coalesced rw3 dword + one dword store.
// ---------------------------------------------------------------------------
__global__ __launch_bounds__(256, 8) void k_main(const float* __restrict__ in,
                                                 const float* __restrict__ w,
                                                 const float* __restrict__ bias,
                                                 const float* __restrict__ dbias,
                                                 const float* __restrict__ rs,
                                                 const float* __restrict__ tsp,
                                                 const float* __restrict__ rw3,
                                                 float* __restrict__ out) {
    __shared__ float inRow[NN * LL];     // 8KB
    __shared__ float tots[LL];
    __shared__ float a2s[FF], rwDs[FF];
    const int t = threadIdx.x;
    const int blk = blockIdx.x;          // b*N + i
    const int b = blk >> 7, i = blk & 127;

    // stage input row (coalesced float4)
    const float4* src4 = reinterpret_cast<const float4*>(in + (size_t)blk * (NN * LL));
    float4* dst4 = reinterpret_cast<float4*>(inRow);
    dst4[t] = src4[t];
    dst4[t + 256] = src4[t + 256];

    if (t < LL) {    // totsum[l] from 32 partial slots (L2-resident, 2KB)
        float s = 0.f;
        const float* tb = tsp + (size_t)b * 32 * LL + t;
#pragma unroll
        for (int sl = 0; sl < 32; ++sl) s += tb[sl * LL];
        tots[t] = s * INV_NAVG;
    }
    __syncthreads();

    if (t < FF) {    // a2s = rs_i.w2 + tot.w1 + bias ; rwDs = rs_i.w4 + tot.w5 + dbias
        float a = bias[t], d = dbias[t];
#pragma unroll
        for (int q = 0; q < LL; ++q) {
            float rv = rs[(size_t)blk * LL + q];   // uniform -> scalar load
            float tv = tots[q];
            a += rv * w[(q * 6 + 2) * FF + t] + tv * w[(q * 6 + 1) * FF + t];
            d += rv * w[(q * 6 + 4) * FF + t] + tv * w[(q * 6 + 5) * FF + t];
        }
        a2s[t] = a; rwDs[t] = d;
    }
    __syncthreads();

    const int f = t & 31, jg = t >> 5;   // 8 j-groups
    float w0r[LL];
#pragma unroll
    for (int q = 0; q < LL; ++q) w0r[q] = w[q * 6 * FF + f];
    const float a2v = a2s[f], rwDv = rwDs[f];
    const float* rw3b = rw3 + (size_t)b * NN * FF + f;
    float* outb = out + (size_t)blk * NN * FF + f;

#pragma unroll 4
    for (int k = 0; k < 16; ++k) {
        int j = jg + 8 * k;
        float acc = a2v + rw3b[(size_t)j * FF] + ((j == i) ? rwDv : 0.f);
        const float4* xr = reinterpret_cast<const float4*>(&inRow[j * LL]);
        float4 x0 = xr[0], x1 = xr[1], x2 = xr[2], x3 = xr[3];
        acc += x0.x * w0r[0] + x0.y * w0r[1] + x0.z * w0r[2] + x0.w * w0r[3];
        acc += x1.x * w0r[4] + x1.y * w0r[5] + x1.z * w0r[6] + x1.w * w0r[7];
        acc += x2.x * w0r[8] + x2.y * w0r[9] + x2.z * w0r[10] + x2.w * w0r[11];
        acc += x3.x * w0r[12] + x3.y * w0r[13] + x3.z * w0r[14] + x3.w * w0r[15];
        outb[(size_t)j * FF] = fmaxf(acc, 0.f);
    }
}

extern "C" void kernel_launch(void* const* d_in, const int* in_sizes, int n_in,
                              void* d_out, int out_size, void* d_ws, size_t ws_size,
                              hipStream_t stream) {
    const float* in    = (const float*)d_in[0];   // [B,N,N,L] fp32
    const float* w     = (const float*)d_in[1];   // [L,6,F]
    const float* bias  = (const float*)d_in[2];   // [F]
    const float* dbias = (const float*)d_in[3];   // [F]
    float* out = (float*)d_out;                   // [B,N,N,F] fp32
    float* ws  = (float*)d_ws;

    float* rs  = ws;                                   // B*N*L   = 65536 floats
    float* tsp = rs  + (size_t)BB * NN * LL;           // B*32*L  = 16384
    float* rw3 = tsp + (size_t)BB * 32 * LL;           // B*N*F   = 131072

    k_rowsum<<<BB * NN / 4, 256, 0, stream>>>(in, w, rs, tsp, rw3);
    k_main  <<<BB * NN,     256, 0, stream>>>(in, w, bias, dbias, rs, tsp, rw3, out);
}

// Round 6
// 43.527 us; speedup vs baseline: 4.3920x; 4.3920x over previous
//
#include <hip/hip_runtime.h>

// Problem constants (fixed by the reference): B=32, N=128, L=16, F=32, NAVG=50
#define BB 32
#define NN 128
#define LL 16
#define FF 32
constexpr float INV_NAVG = 1.0f / 50.0f;

// ---------------------------------------------------------------------------
// Kernel A: per 4 rows (b,i):
//   rs[b,i,l]   = (1/NAVG) * sum_j in[b,i,j,l]          (scaled rowsum)
//   rw3[b,i,f]  = sum_l rs[b,i,l] * w[l,3,f]            (op3 j-broadcast vec)
// 1024 blocks x 256 threads. Coalesced float4 loads, LDS tree reduce.
// ---------------------------------------------------------------------------
__global__ __launch_bounds__(256) void k_rowsum(const float* __restrict__ in,
                                                const float* __restrict__ w,
                                                float* __restrict__ rs,
                                                float* __restrict__ rw3) {
    __shared__ float4 red4[4][256];      // 16KB
    const int t = threadIdx.x;
    const int blk = blockIdx.x;
    const int rowBase = blk * 4;         // global row = b*128 + i
    const int b = rowBase >> 7, i0 = rowBase & 127;

    const float4* in4 = reinterpret_cast<const float4*>(in);
#pragma unroll
    for (int r = 0; r < 4; ++r) {
        size_t base = (size_t)(rowBase + r) * (NN * LL / 4);   // 512 float4/row
        float4 u = in4[base + t];
        float4 v = in4[base + t + 256];
        float4 a;
        a.x = u.x + v.x; a.y = u.y + v.y; a.z = u.z + v.z; a.w = u.w + v.w;
        red4[r][t] = a;
    }
    __syncthreads();
#pragma unroll
    for (int s = 32; s >= 1; s >>= 1) {          // reduce j-groups: 64 -> 1
        if (t < s * 4) {
#pragma unroll
            for (int r = 0; r < 4; ++r) {
                float4 a = red4[r][t], c = red4[r][t + s * 4];
                a.x += c.x; a.y += c.y; a.z += c.z; a.w += c.w;
                red4[r][t] = a;
            }
        }
        __syncthreads();
    }
    // red4[r][0..3] now hold RAW row sums (16 floats per row), LDS-broadcastable.

    if (t < 16) {    // scaled rowsum write (r = row, c = float4 chunk)
        int r = t >> 2, c = t & 3;
        float4 v = red4[r][c];
        v.x *= INV_NAVG; v.y *= INV_NAVG; v.z *= INV_NAVG; v.w *= INV_NAVG;
        reinterpret_cast<float4*>(rs)[(size_t)(rowBase + r) * 4 + c] = v;
    }

    if (t < 128) {   // rw3 for the block's 4 rows
        int r = t >> 5, f = t & 31;
        const float* rowRaw = reinterpret_cast<const float*>(&red4[r][0]);
        float v = 0.f;
#pragma unroll
        for (int q = 0; q < LL; ++q)
            v += rowRaw[q] * w[(q * 6 + 3) * FF + f];
        rw3[((size_t)b * NN + i0 + r) * FF + f] = v * INV_NAVG;
    }
}

// ---------------------------------------------------------------------------
// Kernel M: main. 4096 blocks (one (b,i) row each) x 256 threads.
// NO forced occupancy bound (round-5's (256,8) caused a 240MB spill disaster).
// Thread owns 2 f's (f2=t&15) and 16 j's (jsub=t>>4): float2 stores give
// 512B-contiguous wave stores; hot loop reads only LDS + one L2 float2.
// ---------------------------------------------------------------------------
__global__ __launch_bounds__(256) void k_main(const float* __restrict__ in,
                                              const float* __restrict__ w,
                                              const float* __restrict__ bias,
                                              const float* __restrict__ dbias,
                                              const float* __restrict__ rs,
                                              const float* __restrict__ rw3,
                                              float* __restrict__ out) {
    __shared__ float inRow[NN * LL];     // 8KB
    __shared__ float redf[256];
    __shared__ float tots[LL];
    __shared__ float a2s[FF], rwDs[FF];
    const int t = threadIdx.x;
    const int blk = blockIdx.x;          // b*N + i
    const int b = blk >> 7, i = blk & 127;

    // stage input row (coalesced float4)
    const float4* src4 = reinterpret_cast<const float4*>(in + (size_t)blk * (NN * LL));
    float4* dst4 = reinterpret_cast<float4*>(inRow);
    dst4[t] = src4[t];
    dst4[t + 256] = src4[t + 256];

    // totsum partials from rs[b,:,:] (8KB, L2-resident, coalesced)
    {
        const float* rsb = rs + (size_t)b * NN * LL;
        float s = 0.f;
#pragma unroll
        for (int m = 0; m < 8; ++m) s += rsb[t + 256 * m];
        redf[t] = s;     // flat index t: l = t&15, i-group = t>>4
    }
    __syncthreads();
#pragma unroll
    for (int st = 8; st >= 1; st >>= 1) {
        if (t < st * 16) redf[t] += redf[t + st * 16];
        __syncthreads();
    }
    if (t < LL) tots[t] = redf[t] * INV_NAVG;
    __syncthreads();

    if (t < FF) {    // a2s = rs_i.w2 + tot.w1 + bias ; rwDs = rs_i.w4 + tot.w5 + dbias
        float a = bias[t], d = dbias[t];
#pragma unroll
        for (int q = 0; q < LL; ++q) {
            float rv = rs[(size_t)blk * LL + q];   // uniform -> scalar load
            float tv = tots[q];
            a += rv * w[(q * 6 + 2) * FF + t] + tv * w[(q * 6 + 1) * FF + t];
            d += rv * w[(q * 6 + 4) * FF + t] + tv * w[(q * 6 + 5) * FF + t];
        }
        a2s[t] = a; rwDs[t] = d;
    }
    __syncthreads();

    const int f2 = t & 15;               // f = 2*f2, 2*f2+1
    const int jsub = t >> 4;             // 16 j-groups
    float2 w0r[LL];
#pragma unroll
    for (int q = 0; q < LL; ++q)
        w0r[q] = *reinterpret_cast<const float2*>(&w[(q * 6) * FF + 2 * f2]);
    const float2 a2v  = *reinterpret_cast<const float2*>(&a2s[2 * f2]);
    const float2 rwDv = *reinterpret_cast<const float2*>(&rwDs[2 * f2]);
    const float* rw3b = rw3 + (size_t)b * NN * FF + 2 * f2;
    float* outb = out + (size_t)blk * NN * FF + 2 * f2;

#pragma unroll 2
    for (int p = 0; p < 8; ++p) {
        int j = jsub + 16 * p;
        float2 rv = *reinterpret_cast<const float2*>(&rw3b[(size_t)j * FF]);
        float ax = a2v.x + rv.x;
        float ay = a2v.y + rv.y;
        if (j == i) { ax += rwDv.x; ay += rwDv.y; }
        const float4* xr = reinterpret_cast<const float4*>(&inRow[j * LL]);
        float4 x0 = xr[0], x1 = xr[1], x2 = xr[2], x3 = xr[3];
        ax += x0.x * w0r[0].x + x0.y * w0r[1].x + x0.z * w0r[2].x + x0.w * w0r[3].x
            + x1.x * w0r[4].x + x1.y * w0r[5].x + x1.z * w0r[6].x + x1.w * w0r[7].x
            + x2.x * w0r[8].x + x2.y * w0r[9].x + x2.z * w0r[10].x + x2.w * w0r[11].x
            + x3.x * w0r[12].x + x3.y * w0r[13].x + x3.z * w0r[14].x + x3.w * w0r[15].x;
        ay += x0.x * w0r[0].y + x0.y * w0r[1].y + x0.z * w0r[2].y + x0.w * w0r[3].y
            + x1.x * w0r[4].y + x1.y * w0r[5].y + x1.z * w0r[6].y + x1.w * w0r[7].y
            + x2.x * w0r[8].y + x2.y * w0r[9].y + x2.z * w0r[10].y + x2.w * w0r[11].y
            + x3.x * w0r[12].y + x3.y * w0r[13].y + x3.z * w0r[14].y + x3.w * w0r[15].y;
        float2 o;
        o.x = fmaxf(ax, 0.f);
        o.y = fmaxf(ay, 0.f);
        *reinterpret_cast<float2*>(&outb[(size_t)j * FF]) = o;
    }
}

extern "C" void kernel_launch(void* const* d_in, const int* in_sizes, int n_in,
                              void* d_out, int out_size, void* d_ws, size_t ws_size,
                              hipStream_t stream) {
    const float* in    = (const float*)d_in[0];   // [B,N,N,L] fp32
    const float* w     = (const float*)d_in[1];   // [L,6,F]
    const float* bias  = (const float*)d_in[2];   // [F]
    const float* dbias = (const float*)d_in[3];   // [F]
    float* out = (float*)d_out;                   // [B,N,N,F] fp32
    float* ws  = (float*)d_ws;

    float* rs  = ws;                                   // B*N*L = 65536 floats
    float* rw3 = rs + (size_t)BB * NN * LL;            // B*N*F = 131072 floats

    k_rowsum<<<BB * NN / 4, 256, 0, stream>>>(in, w, rs, rw3);
    k_main  <<<BB * NN,     256, 0, stream>>>(in, w, bias, dbias, rs, rw3, out);
}